// Round 7
// baseline (2959.442 us; speedup 1.0000x reference)
//
#include <hip/hip_runtime.h>
#include <cstdint>
#include <math.h>

// SpikingConv2DLayer fused forward, MI355X (gfx950), fp32 exact-path. v5.
//
// v4 post-mortem: fmaf null-result => conv was already contracted; VALUBusy
// derived metric is ~2x-inflated on gfx950 (gfx94x SIMD-16 formula); true
// busy ~33% ~= the 170us fp32-FMA floor. Kernel is latency-bound: ~500 LDS
// reads/chunk/wave with short load->use distance, 2 waves/SIMD. v5: explicit
// A/B register double-buffer over the c-loop (load c+1's x rows + 25 weights
// while FMA-ing c), weights batch-loaded per channel, prep parallelized.
// Scan/store/prefetch structure unchanged (absmax 0.0 in v2..v4).
//
// Exact facts: single fire of exactly 3.0 per neuron (prev never decays);
// loss = 4.5*F/2^26; spread = 3*maxF_t/2^18.

#define NB 32
#define NC 8
#define NT 256
#define NW 128
#define NO 64
#define WT 16
#define TC 8
#define NROWS 12
#define NCHUNK (NT / TC)
#define XCOLS 20
#define XTILE (NC * NROWS * XCOLS)   // 1920 floats

__device__ __forceinline__ void loadx(float2 (&dst)[NROWS][3], const float* base)
{
#pragma unroll
    for (int r = 0; r < NROWS; ++r) {
        dst[r][0] = *(const float2*)(base + r * XCOLS);
        dst[r][1] = *(const float2*)(base + r * XCOLS + 2);
        dst[r][2] = *(const float2*)(base + r * XCOLS + 4);
    }
}

__device__ __forceinline__ void loadw(float (&dst)[25], const float* wbase)
{
#pragma unroll
    for (int i = 0; i < 25; ++i) dst[i] = wbase[i * 64];
}

__device__ __forceinline__ void fmablk(float (&acc)[TC][2],
                                       const float2 (&xr)[NROWS][3],
                                       const float (&wv_)[25])
{
#pragma unroll
    for (int kt = 0; kt < 5; ++kt) {
        float wk0 = wv_[kt * 5 + 0], wk1 = wv_[kt * 5 + 1], wk2 = wv_[kt * 5 + 2];
        float wk3 = wv_[kt * 5 + 3], wk4 = wv_[kt * 5 + 4];
#pragma unroll
        for (int t = 0; t < TC; ++t) {
            float2 a = xr[t + kt][0], b2 = xr[t + kt][1], c2 = xr[t + kt][2];
            float u0 = acc[t][0], u1 = acc[t][1];
            u0 = fmaf(wk0, a.x,  u0);
            u0 = fmaf(wk1, a.y,  u0);
            u0 = fmaf(wk2, b2.x, u0);
            u0 = fmaf(wk3, b2.y, u0);
            u0 = fmaf(wk4, c2.x, u0);
            u1 = fmaf(wk0, a.y,  u1);
            u1 = fmaf(wk1, b2.x, u1);
            u1 = fmaf(wk2, b2.y, u1);
            u1 = fmaf(wk3, c2.x, u1);
            u1 = fmaf(wk4, c2.y, u1);
            acc[t][0] = u0; acc[t][1] = u1;
        }
    }
}

__global__ __launch_bounds__(1024)
void prep_kernel(const float* __restrict__ w, float* __restrict__ d3,
                 float* __restrict__ invn, unsigned int* __restrict__ gfires)
{
    __shared__ float wsh[NO * 200];
    const int tid = threadIdx.x;
    const int bid = blockIdx.x;            // 16 blocks x 256 pairs
    for (int i = tid; i < NO * 200; i += 1024) wsh[i] = w[i];
    if (bid == 0 && tid < NT) gfires[tid] = 0u;
    __syncthreads();
    if (tid < 256) {
        int idx = bid * 256 + tid;
        int o = idx >> 6, e = idx & 63;
        float acc = 0.0f;
#pragma unroll
        for (int i = 0; i < 200; i += 4) {
            float4 av = *(const float4*)&wsh[o * 200 + i];
            float4 bv = *(const float4*)&wsh[e * 200 + i];
            acc += av.x * bv.x + av.y * bv.y + av.z * bv.z + av.w * bv.w;
        }
        d3[idx] = 3.0f * acc;              // symmetric, includes spike value 3
        if (o == e) invn[o] = 1.0f / (acc + 1e-8f);
    }
}

__global__ __launch_bounds__(512, 2)
void spk_kernel(const float* __restrict__ x, const float* __restrict__ wglob,
                const float* __restrict__ bias, const float* __restrict__ beta_p,
                const float* __restrict__ d3g, const float* __restrict__ invng,
                float* __restrict__ out, unsigned int* __restrict__ gfires)
{
    __shared__ float wsm[NC * 25 * NO];           // [c][kt][kw][co] 51200 B, lane-stride-1
    __shared__ float d3s[NO * NO];                // [c][co] (symmetric) 16384 B
    __shared__ float xsh[2][NC][NROWS][XCOLS];    // 15360 B double-buffered x tile
    __shared__ unsigned short tf[2][NO][8];       // fire-step codes (tfc0|tfc1<<8) 2048 B
    __shared__ unsigned int sf[NT];               // per-t fire counts 1024 B

    const int tid  = threadIdx.x;
    const int lane = tid & 63;        // = cout in conv+scan
    const int wv   = tid >> 6;        // wave 0..7 owns cols 2wv, 2wv+1
    const int bb   = blockIdx.x >> 3;
    const int w0   = (blockIdx.x & 7) * WT;

    // ---- init LDS ----
    for (int i = tid; i < NC * 25 * NO; i += 512) {
        int co = i & 63; int r = i >> 6;          // r = (c*5+kt)*5+kw
        int kw = r % 5; int r2 = r / 5; int kt = r2 % 5; int c = r2 / 5;
        wsm[i] = wglob[((co * NC + c) * 5 + kt) * 5 + kw];
    }
    for (int i = tid; i < NO * NO; i += 512) d3s[i] = d3g[i];
    for (int i = tid; i < NT; i += 512) sf[i] = 0u;

    const size_t xbbase = (size_t)bb * NC * NT * NW;

    // ---- per-thread static prefetch descriptors ----
    const float* pf_ptr[4];
    int  pf_idx[4];
    int  pf_row[4];
    bool pf_okw[4];
#pragma unroll
    for (int k = 0; k < 4; ++k) {
        int i = tid + k * 512;
        if (i < XTILE) {
            int c = i / (NROWS * XCOLS); int rem = i - c * (NROWS * XCOLS);
            int row = rem / XCOLS; int col = rem - row * XCOLS;
            int wg = w0 + col - 2;
            pf_idx[k] = i; pf_row[k] = row;
            pf_okw[k] = (wg >= 0 && wg < NW);
            pf_ptr[k] = x + xbbase + ((size_t)c * NT + 6 + row) * NW + (wg < 0 ? 0 : wg);
        } else { pf_idx[k] = -1; pf_row[k] = 0; pf_okw[k] = false; pf_ptr[k] = x; }
    }

    // ---- per-thread static store descriptors ----
    const int sq = tid & 3;
    const int srow = tid >> 2;
    int    sp_tfidx[4];
    int    sp_tt[4];
    float* sp_out[4];
#pragma unroll
    for (int p = 0; p < 4; ++p) {
        int rowi = p * 128 + srow;
        int co = rowi >> 3, tt = rowi & 7;
        sp_tfidx[p] = co * 8 + sq * 2;
        sp_tt[p] = tt;
        sp_out[p] = out + (((size_t)(bb * NO + co) * NT + tt) * NW + w0 + sq * 4);
    }

    // ---- stage chunk 0 -> buf 0 (rows -2..9) ----
#pragma unroll
    for (int k = 0; k < 4; ++k) {
        int i = tid + k * 512;
        if (i < XTILE) {
            int c = i / (NROWS * XCOLS); int rem = i - c * (NROWS * XCOLS);
            int row = rem / XCOLS; int col = rem - row * XCOLS;
            int tg = row - 2, wg = w0 + col - 2;
            float v = 0.0f;
            if (tg >= 0 && tg < NT && wg >= 0 && wg < NW)
                v = x[xbbase + ((size_t)c * NT + tg) * NW + wg];
            (&xsh[0][0][0][0])[i] = v;
        }
    }

    const float invn = invng[lane];
    const float bco  = bias[lane];
    const float beta = beta_p[0];
    const float omb  = 1.0f - beta;

    float mem0 = 0.f, mem1 = 0.f;
    unsigned int fired = 0u;
    unsigned long long pm0 = 0ull, pm1 = 0ull;

    __syncthreads();

#pragma unroll 1
    for (int ch = 0; ch < NCHUNK; ++ch) {
        const int buf = ch & 1;
        const int tbase = ch * TC;

        // ---- (a) prefetch next x tile into registers (HBM latency under conv) ----
        float sr[4];
        if (ch + 1 < NCHUNK) {
#pragma unroll
            for (int k = 0; k < 4; ++k) {
                float v = 0.0f;
                int tg = (ch << 3) + 6 + pf_row[k];
                if (pf_okw[k] && tg < NT)
                    v = pf_ptr[k][(size_t)ch * (TC * NW)];
                sr[k] = v;
            }
        }

        // ---- (b) store previous chunk's output tile (overlaps conv) ----
        if (ch > 0) {
            const unsigned short* tfp = &tf[buf ^ 1][0][0];
            const size_t oadv = (size_t)(ch - 1) * (TC * NW);
#pragma unroll
            for (int p = 0; p < 4; ++p) {
                unsigned int codes = *(const unsigned int*)(tfp + sp_tfidx[p]);
                unsigned int tt = (unsigned)sp_tt[p];
                float4 v;
                v.x = (((codes      ) & 0xffu) == tt) ? 3.0f : 0.0f;
                v.y = (((codes >>  8) & 0xffu) == tt) ? 3.0f : 0.0f;
                v.z = (((codes >> 16) & 0xffu) == tt) ? 3.0f : 0.0f;
                v.w = (((codes >> 24) & 0xffu) == tt) ? 3.0f : 0.0f;
                *(float4*)(sp_out[p] + oadv) = v;
            }
        }

        // ---- (c) conv: explicit A/B register pipeline over c ----
        float acc[TC][2];
#pragma unroll
        for (int t = 0; t < TC; ++t) { acc[t][0] = 0.f; acc[t][1] = 0.f; }

        const float* xb = &xsh[buf][0][0][0] + 2 * wv;      // c-stride = NROWS*XCOLS
        {
            float2 xA[NROWS][3]; float wA[25];
            loadx(xA, xb);
            loadw(wA, &wsm[lane]);
#pragma unroll 1
            for (int cc = 0; cc < 4; ++cc) {
                float2 xB[NROWS][3]; float wB[25];
                loadx(xB, xb + (2 * cc + 1) * (NROWS * XCOLS));
                loadw(wB, &wsm[(2 * cc + 1) * 25 * 64 + lane]);
                fmablk(acc, xA, wA);                        // hides B's LDS loads
                if (cc < 3) {
                    loadx(xA, xb + (2 * cc + 2) * (NROWS * XCOLS));
                    loadw(wA, &wsm[(2 * cc + 2) * 25 * 64 + lane]);
                }
                fmablk(acc, xB, wB);                        // hides A's LDS loads
            }
        }

        // ---- (d) scan: 8 steps, barrier-free (ballot fire masks) ----
        unsigned int tfc0 = 0xffu, tfc1 = 0xffu;
#pragma unroll
        for (int tt = 0; tt < TC; ++tt) {
            float r0 = 0.f, r1 = 0.f;
            if (pm0 | pm1) {
                unsigned long long m = pm0;
                while (m) { int c = __builtin_ctzll(m); m &= m - 1; r0 += d3s[c * 64 + lane]; }
                m = pm1;
                while (m) { int c = __builtin_ctzll(m); m &= m - 1; r1 += d3s[c * 64 + lane]; }
            }
            mem0 = (mem0 - r0) * beta + acc[tt][0] * omb;
            mem1 = (mem1 - r1) * beta + acc[tt][1] * omb;
            bool f0 = !(fired & 1u) && (mem0 * invn - bco > 0.0f);
            bool f1 = !(fired & 2u) && (mem1 * invn - bco > 0.0f);
            pm0 = __ballot(f0);
            pm1 = __ballot(f1);
            if (f0) { fired |= 1u; tfc0 = (unsigned)tt; }
            if (f1) { fired |= 2u; tfc1 = (unsigned)tt; }
            unsigned int cnt = (unsigned)(__popcll(pm0) + __popcll(pm1));
            if (lane == 0 && cnt) atomicAdd(&sf[tbase + tt], cnt);
        }
        tf[buf][lane][wv] = (unsigned short)(tfc0 | (tfc1 << 8));

        // ---- (e) commit prefetched tile into other buffer ----
        if (ch + 1 < NCHUNK) {
            float* dst = &xsh[buf ^ 1][0][0][0];
#pragma unroll
            for (int k = 0; k < 4; ++k) {
                if (pf_idx[k] >= 0) dst[pf_idx[k]] = sr[k];
            }
        }
        __syncthreads();
    }

    // ---- epilogue: store last chunk's tile ----
    {
        const unsigned short* tfp = &tf[(NCHUNK - 1) & 1][0][0];
        const size_t oadv = (size_t)(NCHUNK - 1) * (TC * NW);
#pragma unroll
        for (int p = 0; p < 4; ++p) {
            unsigned int codes = *(const unsigned int*)(tfp + sp_tfidx[p]);
            unsigned int tt = (unsigned)sp_tt[p];
            float4 v;
            v.x = (((codes      ) & 0xffu) == tt) ? 3.0f : 0.0f;
            v.y = (((codes >>  8) & 0xffu) == tt) ? 3.0f : 0.0f;
            v.z = (((codes >> 16) & 0xffu) == tt) ? 3.0f : 0.0f;
            v.w = (((codes >> 24) & 0xffu) == tt) ? 3.0f : 0.0f;
            *(float4*)(sp_out[p] + oadv) = v;
        }
    }

    if (tid < NT) atomicAdd(&gfires[tid], sf[tid]);
}

__global__ __launch_bounds__(256)
void fin_kernel(const unsigned int* __restrict__ gfires, float* __restrict__ out)
{
    const int tid = threadIdx.x;
    unsigned int v = gfires[tid];
    unsigned int s = v, m = v;
    for (int off = 32; off > 0; off >>= 1) {
        s += __shfl_down(s, off);
        unsigned int o = __shfl_down(m, off);
        m = m > o ? m : o;
    }
    __shared__ unsigned int ls[4], lm[4];
    if ((tid & 63) == 0) { ls[tid >> 6] = s; lm[tid >> 6] = m; }
    __syncthreads();
    if (tid == 0) {
        unsigned int ts = 0, tm = 0;
        for (int i = 0; i < 4; ++i) { ts += ls[i]; tm = tm > lm[i] ? tm : lm[i]; }
        out[67108864] = 4.5f * (float)ts / 67108864.0f;   // 0.5*9*F/2^26
        out[67108865] = 3.0f * (float)tm / 262144.0f;     // 3*maxF/(32*64*128)
    }
}

extern "C" void kernel_launch(void* const* d_in, const int* in_sizes, int n_in,
                              void* d_out, int out_size, void* d_ws, size_t ws_size,
                              hipStream_t stream)
{
    const float* x    = (const float*)d_in[0];
    const float* w    = (const float*)d_in[1];
    const float* b    = (const float*)d_in[2];
    const float* beta = (const float*)d_in[3];
    // d_in[4] = sigma: unused in forward

    float* out  = (float*)d_out;
    float* wsf  = (float*)d_ws;
    float* d3   = wsf;                               // 4096 floats
    float* invn = wsf + 4096;                        // 64 floats
    unsigned int* gf = (unsigned int*)(wsf + 4160);  // 256 u32

    prep_kernel<<<16, 1024, 0, stream>>>(w, d3, invn, gf);
    spk_kernel<<<256, 512, 0, stream>>>(x, w, b, beta, d3, invn, out, gf);
    fin_kernel<<<1, 256, 0, stream>>>(gf, out);
}

// Round 10
// 854.183 us; speedup vs baseline: 3.4646x; 3.4646x over previous
//
#include <hip/hip_runtime.h>
#include <cstdint>
#include <math.h>

// SpikingConv2DLayer fused forward, MI355X (gfx950), fp32 exact-path. v6
// (2nd resubmit — rounds 8 and 9 were GPUAcquisitionTimeout; never ran).
//
// v5 post-mortem: explicit A/B reg double-buffer (~240 live floats) under a
// 128-VGPR cap (empirical: __launch_bounds__ 2nd arg = min BLOCKS/CU, so
// (512,2) -> 16 waves/CU -> 128 regs) => massive scratch spill (FETCH 4.2GB,
// WRITE 8.3GB). Reverted. v6 attacks the v4-diagnosed latency-boundedness
// (true VALU busy ~33% at 2 waves/SIMD) with TLP instead of ILP: 1024-thread
// blocks, 16 waves, ONE column per wave -> 4 waves/SIMD at <=128 VGPRs
// (live set ~110: 60-float x window + 5 w + 8 acc + scan state).
// Structure (ballot scan, code-table store, double-buffered x tile, one
// barrier per chunk) unchanged from v4 (absmax 0.0 in v2..v5).
//
// Exact facts: single fire of exactly 3.0 per neuron (prev never decays);
// loss = 4.5*F/2^26; spread = 3*maxF_t/2^18.

#define NB 32
#define NC 8
#define NT 256
#define NW 128
#define NO 64
#define WT 16
#define TC 8
#define NROWS 12
#define NCHUNK (NT / TC)
#define XCOLS 20
#define XTILE (NC * NROWS * XCOLS)   // 1920 floats

__global__ __launch_bounds__(1024)
void prep_kernel(const float* __restrict__ w, float* __restrict__ d3,
                 float* __restrict__ invn, unsigned int* __restrict__ gfires)
{
    __shared__ float wsh[NO * 200];
    const int tid = threadIdx.x;
    const int bid = blockIdx.x;            // 16 blocks x 256 pairs
    for (int i = tid; i < NO * 200; i += 1024) wsh[i] = w[i];
    if (bid == 0 && tid < NT) gfires[tid] = 0u;
    __syncthreads();
    if (tid < 256) {
        int idx = bid * 256 + tid;
        int o = idx >> 6, e = idx & 63;
        float acc = 0.0f;
#pragma unroll
        for (int i = 0; i < 200; i += 4) {
            float4 av = *(const float4*)&wsh[o * 200 + i];
            float4 bv = *(const float4*)&wsh[e * 200 + i];
            acc += av.x * bv.x + av.y * bv.y + av.z * bv.z + av.w * bv.w;
        }
        d3[idx] = 3.0f * acc;              // symmetric, includes spike value 3
        if (o == e) invn[o] = 1.0f / (acc + 1e-8f);
    }
}

__global__ __launch_bounds__(1024, 1)
void spk_kernel(const float* __restrict__ x, const float* __restrict__ wglob,
                const float* __restrict__ bias, const float* __restrict__ beta_p,
                const float* __restrict__ d3g, const float* __restrict__ invng,
                float* __restrict__ out, unsigned int* __restrict__ gfires)
{
    __shared__ float wsm[NC * 25 * NO];           // [c][kt][kw][co] 51200 B, lane-stride-1
    __shared__ float d3s[NO * NO];                // [c][co] (symmetric) 16384 B
    __shared__ float xsh[2][NC][NROWS][XCOLS];    // 15360 B double-buffered x tile
    __shared__ unsigned char tf[2][NO][16];       // fire-step code per (co, col) 2048 B
    __shared__ unsigned int sf[NT];               // per-t fire counts 1024 B

    const int tid  = threadIdx.x;
    const int lane = tid & 63;        // = cout in conv+scan
    const int wv   = tid >> 6;        // wave 0..15 owns column wv
    const int bb   = blockIdx.x >> 3;
    const int w0   = (blockIdx.x & 7) * WT;

    // ---- init LDS ----
    for (int i = tid; i < NC * 25 * NO; i += 1024) {
        int co = i & 63; int r = i >> 6;          // r = (c*5+kt)*5+kw
        int kw = r % 5; int r2 = r / 5; int kt = r2 % 5; int c = r2 / 5;
        wsm[i] = wglob[((co * NC + c) * 5 + kt) * 5 + kw];
    }
    for (int i = tid; i < NO * NO; i += 1024) d3s[i] = d3g[i];
    if (tid < NT) sf[tid] = 0u;

    const size_t xbbase = (size_t)bb * NC * NT * NW;

    // ---- per-thread static prefetch descriptors (2 elements/thread) ----
    const float* pf_ptr[2];
    int  pf_idx[2];
    int  pf_row[2];
    bool pf_okw[2];
#pragma unroll
    for (int k = 0; k < 2; ++k) {
        int i = tid + k * 1024;
        if (i < XTILE) {
            int c = i / (NROWS * XCOLS); int rem = i - c * (NROWS * XCOLS);
            int row = rem / XCOLS; int col = rem - row * XCOLS;
            int wg = w0 + col - 2;
            pf_idx[k] = i; pf_row[k] = row;
            pf_okw[k] = (wg >= 0 && wg < NW);
            pf_ptr[k] = x + xbbase + ((size_t)c * NT + 6 + row) * NW + (wg < 0 ? 0 : wg);
        } else { pf_idx[k] = -1; pf_row[k] = 0; pf_okw[k] = false; pf_ptr[k] = x; }
    }

    // ---- per-thread static store descriptors (2 float4/thread) ----
    const int sq = tid & 3;
    const int srow = tid >> 2;                    // 0..255
    int    sp_tfidx[2];
    int    sp_tt[2];
    float* sp_out[2];
#pragma unroll
    for (int p = 0; p < 2; ++p) {
        int rowi = p * 256 + srow;                // 0..511
        int co = rowi >> 3, tt = rowi & 7;
        sp_tfidx[p] = co * 16 + sq * 4;           // u32-aligned u8 index
        sp_tt[p] = tt;
        sp_out[p] = out + (((size_t)(bb * NO + co) * NT + tt) * NW + w0 + sq * 4);
    }

    // ---- stage chunk 0 -> buf 0 (rows -2..9) ----
#pragma unroll
    for (int k = 0; k < 2; ++k) {
        int i = tid + k * 1024;
        if (i < XTILE) {
            int c = i / (NROWS * XCOLS); int rem = i - c * (NROWS * XCOLS);
            int row = rem / XCOLS; int col = rem - row * XCOLS;
            int tg = row - 2, wg = w0 + col - 2;
            float v = 0.0f;
            if (tg >= 0 && tg < NT && wg >= 0 && wg < NW)
                v = x[xbbase + ((size_t)c * NT + tg) * NW + wg];
            (&xsh[0][0][0][0])[i] = v;
        }
    }

    const float invn = invng[lane];
    const float bco  = bias[lane];
    const float beta = beta_p[0];
    const float omb  = 1.0f - beta;

    float mem0 = 0.f;
    bool fired = false;
    unsigned long long pm0 = 0ull;

    __syncthreads();

#pragma unroll 1
    for (int ch = 0; ch < NCHUNK; ++ch) {
        const int buf = ch & 1;
        const int tbase = ch * TC;

        // ---- (a) prefetch next x tile into registers (HBM latency under conv) ----
        float sr[2];
        if (ch + 1 < NCHUNK) {
#pragma unroll
            for (int k = 0; k < 2; ++k) {
                float v = 0.0f;
                int tg = (ch << 3) + 6 + pf_row[k];
                if (pf_okw[k] && tg < NT)
                    v = pf_ptr[k][(size_t)ch * (TC * NW)];
                sr[k] = v;
            }
        }

        // ---- (b) store previous chunk's output tile (overlaps conv) ----
        if (ch > 0) {
            const unsigned char* tfp = &tf[buf ^ 1][0][0];
            const size_t oadv = (size_t)(ch - 1) * (TC * NW);
#pragma unroll
            for (int p = 0; p < 2; ++p) {
                unsigned int codes = *(const unsigned int*)(tfp + sp_tfidx[p]);
                unsigned int tt = (unsigned)sp_tt[p];
                float4 v;
                v.x = (((codes      ) & 0xffu) == tt) ? 3.0f : 0.0f;
                v.y = (((codes >>  8) & 0xffu) == tt) ? 3.0f : 0.0f;
                v.z = (((codes >> 16) & 0xffu) == tt) ? 3.0f : 0.0f;
                v.w = (((codes >> 24) & 0xffu) == tt) ? 3.0f : 0.0f;
                *(float4*)(sp_out[p] + oadv) = v;
            }
        }

        // ---- (c) conv: 1 column/wave, scalar broadcast x reads ----
        float acc[TC];
#pragma unroll
        for (int t = 0; t < TC; ++t) acc[t] = 0.f;

#pragma unroll 1
        for (int c = 0; c < NC; ++c) {
            float xr[NROWS][5];
#pragma unroll
            for (int r = 0; r < NROWS; ++r) {
#pragma unroll
                for (int j = 0; j < 5; ++j)
                    xr[r][j] = xsh[buf][c][r][wv + j];
            }
#pragma unroll
            for (int kt = 0; kt < 5; ++kt) {
                const float* wp = &wsm[((c * 5 + kt) * 5) * 64 + lane];
                float wk0 = wp[0], wk1 = wp[64], wk2 = wp[128], wk3 = wp[192], wk4 = wp[256];
#pragma unroll
                for (int t = 0; t < TC; ++t) {
                    float u = acc[t];
                    u = fmaf(wk0, xr[t + kt][0], u);
                    u = fmaf(wk1, xr[t + kt][1], u);
                    u = fmaf(wk2, xr[t + kt][2], u);
                    u = fmaf(wk3, xr[t + kt][3], u);
                    u = fmaf(wk4, xr[t + kt][4], u);
                    acc[t] = u;
                }
            }
        }

        // ---- (d) scan: 8 steps, barrier-free (ballot fire mask) ----
        unsigned int tfc0 = 0xffu;
#pragma unroll
        for (int tt = 0; tt < TC; ++tt) {
            float r0 = 0.f;
            if (pm0) {
                unsigned long long m = pm0;
                while (m) { int c = __builtin_ctzll(m); m &= m - 1; r0 += d3s[c * 64 + lane]; }
            }
            mem0 = (mem0 - r0) * beta + acc[tt] * omb;
            bool f0 = !fired && (mem0 * invn - bco > 0.0f);
            pm0 = __ballot(f0);
            if (f0) { fired = true; tfc0 = (unsigned)tt; }
            unsigned int cnt = (unsigned)__popcll(pm0);
            if (lane == 0 && cnt) atomicAdd(&sf[tbase + tt], cnt);
        }
        tf[buf][lane][wv] = (unsigned char)tfc0;

        // ---- (e) commit prefetched tile into other buffer ----
        if (ch + 1 < NCHUNK) {
            float* dst = &xsh[buf ^ 1][0][0][0];
#pragma unroll
            for (int k = 0; k < 2; ++k) {
                if (pf_idx[k] >= 0) dst[pf_idx[k]] = sr[k];
            }
        }
        __syncthreads();
    }

    // ---- epilogue: store last chunk's tile ----
    {
        const unsigned char* tfp = &tf[(NCHUNK - 1) & 1][0][0];
        const size_t oadv = (size_t)(NCHUNK - 1) * (TC * NW);
#pragma unroll
        for (int p = 0; p < 2; ++p) {
            unsigned int codes = *(const unsigned int*)(tfp + sp_tfidx[p]);
            unsigned int tt = (unsigned)sp_tt[p];
            float4 v;
            v.x = (((codes      ) & 0xffu) == tt) ? 3.0f : 0.0f;
            v.y = (((codes >>  8) & 0xffu) == tt) ? 3.0f : 0.0f;
            v.z = (((codes >> 16) & 0xffu) == tt) ? 3.0f : 0.0f;
            v.w = (((codes >> 24) & 0xffu) == tt) ? 3.0f : 0.0f;
            *(float4*)(sp_out[p] + oadv) = v;
        }
    }

    if (tid < NT) atomicAdd(&gfires[tid], sf[tid]);
}

__global__ __launch_bounds__(256)
void fin_kernel(const unsigned int* __restrict__ gfires, float* __restrict__ out)
{
    const int tid = threadIdx.x;
    unsigned int v = gfires[tid];
    unsigned int s = v, m = v;
    for (int off = 32; off > 0; off >>= 1) {
        s += __shfl_down(s, off);
        unsigned int o = __shfl_down(m, off);
        m = m > o ? m : o;
    }
    __shared__ unsigned int ls[4], lm[4];
    if ((tid & 63) == 0) { ls[tid >> 6] = s; lm[tid >> 6] = m; }
    __syncthreads();
    if (tid == 0) {
        unsigned int ts = 0, tm = 0;
        for (int i = 0; i < 4; ++i) { ts += ls[i]; tm = tm > lm[i] ? tm : lm[i]; }
        out[67108864] = 4.5f * (float)ts / 67108864.0f;   // 0.5*9*F/2^26
        out[67108865] = 3.0f * (float)tm / 262144.0f;     // 3*maxF/(32*64*128)
    }
}

extern "C" void kernel_launch(void* const* d_in, const int* in_sizes, int n_in,
                              void* d_out, int out_size, void* d_ws, size_t ws_size,
                              hipStream_t stream)
{
    const float* x    = (const float*)d_in[0];
    const float* w    = (const float*)d_in[1];
    const float* b    = (const float*)d_in[2];
    const float* beta = (const float*)d_in[3];
    // d_in[4] = sigma: unused in forward

    float* out  = (float*)d_out;
    float* wsf  = (float*)d_ws;
    float* d3   = wsf;                               // 4096 floats
    float* invn = wsf + 4096;                        // 64 floats
    unsigned int* gf = (unsigned int*)(wsf + 4160);  // 256 u32

    prep_kernel<<<16, 1024, 0, stream>>>(w, d3, invn, gf);
    spk_kernel<<<256, 1024, 0, stream>>>(x, w, b, beta, d3, invn, out, gf);
    fin_kernel<<<1, 256, 0, stream>>>(gf, out);
}